// Round 1
// baseline (120.682 us; speedup 1.0000x reference)
//
#include <hip/hip_runtime.h>
#include <hip/hip_bf16.h>
#include <hip/hip_fp8.h>
#include <math.h>

typedef float f32x4 __attribute__((ext_vector_type(4)));
typedef int   i32x4 __attribute__((ext_vector_type(4)));
typedef int   v8i   __attribute__((ext_vector_type(8)));

constexpr int Nn = 8192;   // B*S
constexpr int Dd = 256;    // feature dim (== bytes per fp8 row)
constexpr float LOG2E     = 1.4426950408889634f;
constexpr float SIM_SCALE = 20.0f * LOG2E;   // (1/tau)*log2(e), tau=0.05
constexpr float SIM_BIAS  = -20.0f * LOG2E;  // fixed max = 1/tau (|q.k|<=1)
constexpr int   SCALE1    = 0x7F7F7F7F;      // E8M0 127 = 2^0 in every byte

// async global->LDS DMA, 16B/lane; LDS dst = wave-uniform base + lane*16.
typedef __attribute__((address_space(1))) const unsigned int gu32;
typedef __attribute__((address_space(3))) unsigned int lu32;
__device__ __forceinline__ void gload16(const unsigned char* g, unsigned char* l) {
  __builtin_amdgcn_global_load_lds((gu32*)(uintptr_t)g, (lu32*)(uintptr_t)l, 16, 0, 0);
}

// ---------------------------------------------------------------------------
// Kernel 1: L2-normalize rows -> fp8 e4m3; init cbias (SIM_BIAS pre-folded) /
// g_all / g_pos.
// ---------------------------------------------------------------------------
__global__ __launch_bounds__(256) void prep_kernel(const float* __restrict__ logits,
                                                   const float* __restrict__ labels,
                                                   const int* __restrict__ pad,
                                                   unsigned char* __restrict__ qb,
                                                   unsigned char* __restrict__ kb,
                                                   float* __restrict__ cbias,
                                                   float* __restrict__ g_all,
                                                   float* __restrict__ g_pos) {
  const int j = blockIdx.x * 256 + threadIdx.x;
  if (j < Nn) {
    cbias[j] = pad[j] ? SIM_BIAS : -1e30f;   // SIM_BIAS folded in (col term)
    g_all[j] = 0.0f;
    g_pos[j] = 0.0f;
  }

  const int gw   = (blockIdx.x * 256 + threadIdx.x) >> 6;
  const int lane = threadIdx.x & 63;
  const float* src;
  unsigned char* dst;
  int row;
  if (gw < Nn) { src = logits; dst = qb; row = gw; }
  else         { src = labels; dst = kb; row = gw - Nn; }

  const float4 v = *reinterpret_cast<const float4*>(src + (size_t)row * Dd + lane * 4);
  float ss = v.x * v.x + v.y * v.y + v.z * v.z + v.w * v.w;
#pragma unroll
  for (int m = 32; m >= 1; m >>= 1) ss += __shfl_xor(ss, m);
  const float scale = 1.0f / fmaxf(sqrtf(ss), 1e-12f);

  const __hip_fp8_e4m3 e0(v.x * scale);
  const __hip_fp8_e4m3 e1(v.y * scale);
  const __hip_fp8_e4m3 e2(v.z * scale);
  const __hip_fp8_e4m3 e3(v.w * scale);
  const unsigned int packed = (unsigned int)e0.__x |
                              ((unsigned int)e1.__x << 8) |
                              ((unsigned int)e2.__x << 16) |
                              ((unsigned int)e3.__x << 24);
  reinterpret_cast<unsigned int*>(dst + (size_t)row * Dd)[lane] = packed;
}

// ---------------------------------------------------------------------------
// Kernel 2: fused sim = Q K^T / tau + dual exp-sum epilogue (all & pos), fp8
// MX-scaled MFMA 16x16x128 (unit scales).
//
// R14 change: tile 128x256 (was 128x128), 512 threads / 8 waves (2 wrow x
// 4 wcol). Per-wave tile stays 64x64 -> MFMA inner loop, fragment layout,
// DMA swizzle (slot = g ^ (r&7)) all IDENTICAL to the verified R13 path.
//   - L2-staged bytes: 268 MB -> 201 MB (-25%)  [largest pipe in the model]
//   - g_all/g_pos atomics: 1.05M -> 0.52M (-50%)
// Epilogue: 64 partials/row (4 wcol-waves x 16 lq) folded to 32 via one
// __shfl_xor(.,8) (lanes lq and lq^8 hold the SAME rows), then the exact
// R13 32-partial swizzled LDS reduction.
// ---------------------------------------------------------------------------
__global__ __launch_bounds__(512) void gemm_lse_kernel(const unsigned char* __restrict__ qb,
                                                       const unsigned char* __restrict__ kb,
                                                       const float* __restrict__ cbias,
                                                       const int* __restrict__ ad,
                                                       float* __restrict__ g_all,
                                                       float* __restrict__ g_pos) {
  __shared__ unsigned char smem[49152];  // As(16K) | Bs(32K); epilogue reuse
  unsigned char* As = smem;              // 128 rows x 128 B
  unsigned char* Bs = smem + 16384;      // 256 rows x 128 B
  float* redA = reinterpret_cast<float*>(smem);         // 128 x 32 partials
  float* redP = reinterpret_cast<float*>(smem) + 4096;  // 128 x 32 partials

  const int tid  = threadIdx.x;
  const int lane = tid & 63;
  const int w    = tid >> 6;        // 0..7
  const int wrow = (w >> 2) * 64;   // 0 or 64
  const int wcol = (w & 3) * 64;    // 0,64,128,192
  const int lq   = lane & 15;
  const int qd   = lane >> 4;
  const int rowBase = blockIdx.x * 128;
  const int colBase = blockIdx.y * 256;

  // staging constants (R13-verified): a wave's iter i fills 8 LDS rows;
  // lane l -> row +(l>>3), logical 16B group (l&7)^(l>>3) (linear LDS dst).
  const int srl = lane >> 3;
  const int cg  = (lane & 7) ^ srl;
  const unsigned char* gA0 = qb + (size_t)(rowBase + (w & 3) * 32 + srl) * Dd + cg * 16;
  const unsigned char* gB0 = kb + (size_t)(colBase + w * 32 + srl) * Dd + cg * 16;

  f32x4 c[4][4];
#pragma unroll
  for (int mt = 0; mt < 4; ++mt)
#pragma unroll
    for (int nt = 0; nt < 4; ++nt)
      c[mt][nt] = (f32x4){0.f, 0.f, 0.f, 0.f};

  for (int kk = 0; kk < 2; ++kk) {
    const int kOff = kk * 128;  // byte offset into the 256 B row
    __syncthreads();  // prior MFMA phase done reading LDS
#pragma unroll
    for (int i = 0; i < 4; ++i) {
      if (w < 4)  // waves 0-3 stage the 128-row A tile (wave-uniform branch)
        gload16(gA0 + (size_t)i * 8 * Dd + kOff, &As[((w & 3) * 32 + i * 8) * 128]);
      // all 8 waves stage the 256-row B tile
      gload16(gB0 + (size_t)i * 8 * Dd + kOff, &Bs[(w * 32 + i * 8) * 128]);
    }
    __syncthreads();  // drains vmcnt (DMA) before fragment reads

    const int g0 = qd << 1;  // lane's first 16B group (K bytes qd*32..+15)
    v8i af[4];
#pragma unroll
    for (int mt = 0; mt < 4; ++mt) {
      const int r = wrow + mt * 16 + lq;
      const i32x4 lo = *reinterpret_cast<const i32x4*>(&As[r * 128 + ((g0 ^ (r & 7)) << 4)]);
      const i32x4 hi = *reinterpret_cast<const i32x4*>(&As[r * 128 + (((g0 + 1) ^ (r & 7)) << 4)]);
      af[mt] = (v8i){lo.x, lo.y, lo.z, lo.w, hi.x, hi.y, hi.z, hi.w};
    }
#pragma unroll
    for (int nt = 0; nt < 4; ++nt) {
      const int r = wcol + nt * 16 + lq;
      const i32x4 lo = *reinterpret_cast<const i32x4*>(&Bs[r * 128 + ((g0 ^ (r & 7)) << 4)]);
      const i32x4 hi = *reinterpret_cast<const i32x4*>(&Bs[r * 128 + (((g0 + 1) ^ (r & 7)) << 4)]);
      const v8i bfq = (v8i){lo.x, lo.y, lo.z, lo.w, hi.x, hi.y, hi.z, hi.w};
#pragma unroll
      for (int mt = 0; mt < 4; ++mt)
        c[mt][nt] = __builtin_amdgcn_mfma_scale_f32_16x16x128_f8f6f4(
            af[mt], bfq, c[mt][nt], 0, 0, 0, SCALE1, 0, SCALE1);
    }
  }

  // ---- epilogue ----
  float colB[4];
  int colAd[4];
#pragma unroll
  for (int nt = 0; nt < 4; ++nt) {
    const int col = colBase + wcol + nt * 16 + lq;
    colB[nt]  = cbias[col];          // SIM_BIAS already folded in prep
    colAd[nt] = ad[col];
  }

  __syncthreads();  // all waves done with As/Bs before reuse as partials

  // after the lq^8 fold: 32 partials per row, owner lanes have lq<8
  const int idx = (w & 3) * 8 + (lane & 7);
  const int g   = idx >> 2;
  const int gi  = idx & 3;

#pragma unroll
  for (int mt = 0; mt < 4; ++mt) {
#pragma unroll
    for (int r = 0; r < 4; ++r) {
      const int row   = wrow + mt * 16 + qd * 4 + r;
      const int rowAd = ad[rowBase + row];
      float a = 0.f, p = 0.f;
#pragma unroll
      for (int nt = 0; nt < 4; ++nt) {
        const float e = __builtin_amdgcn_exp2f(fmaf(c[mt][nt][r], SIM_SCALE, colB[nt]));
        a += e;
        p += (colAd[nt] == rowAd) ? e : 0.f;
      }
      // fold lanes lq and lq^8 (same row, different nt-columns)
      a += __shfl_xor(a, 8);
      p += __shfl_xor(p, 8);
      if (lq < 8) {
        const int off = row * 32 + ((g ^ (row & 7)) << 2) + gi;
        redA[off] = a;
        redP[off] = p;
      }
    }
  }
  __syncthreads();

  if (tid < 128) {
    const int row = tid;
    float a = 0.f, p = 0.f;
#pragma unroll
    for (int gg = 0; gg < 8; ++gg) {
      const int off = row * 32 + ((gg ^ (row & 7)) << 2);
      const f32x4 va = *reinterpret_cast<const f32x4*>(&redA[off]);
      const f32x4 vp = *reinterpret_cast<const f32x4*>(&redP[off]);
      a += (va[0] + va[1]) + (va[2] + va[3]);
      p += (vp[0] + vp[1]) + (vp[2] + vp[3]);
    }
    atomicAdd(&g_all[rowBase + row], a);
    atomicAdd(&g_pos[rowBase + row], p);
  }
}

// ---------------------------------------------------------------------------
// Kernel 3: loss = mean over valid rows of log(g_all) - log(g_pos).
// ---------------------------------------------------------------------------
__global__ __launch_bounds__(1024) void reduce_kernel(const float* __restrict__ g_all,
                                                      const float* __restrict__ g_pos,
                                                      const int* __restrict__ pad,
                                                      float* __restrict__ out) {
  __shared__ float sS[16], sC[16];
  const int t = threadIdx.x;
  float s = 0.f, c = 0.f;
  const float4* ga4 = (const float4*)g_all;
  const float4* gp4 = (const float4*)g_pos;
  const int4*   pd4 = (const int4*)pad;
  for (int i = t; i < Nn / 4; i += 1024) {
    const float4 ga = ga4[i];
    const float4 gp = gp4[i];
    const int4   pd = pd4[i];
    if (pd.x) { s += __logf(ga.x) - __logf(gp.x); c += 1.f; }
    if (pd.y) { s += __logf(ga.y) - __logf(gp.y); c += 1.f; }
    if (pd.z) { s += __logf(ga.z) - __logf(gp.z); c += 1.f; }
    if (pd.w) { s += __logf(ga.w) - __logf(gp.w); c += 1.f; }
  }
#pragma unroll
  for (int m = 32; m >= 1; m >>= 1) {
    s += __shfl_xor(s, m);
    c += __shfl_xor(c, m);
  }
  if ((t & 63) == 0) { sS[t >> 6] = s; sC[t >> 6] = c; }
  __syncthreads();
  if (t == 0) {
    float S = 0.f, C = 0.f;
#pragma unroll
    for (int i = 0; i < 16; ++i) { S += sS[i]; C += sC[i]; }
    out[0] = S / fmaxf(C, 1.0f);
  }
}

extern "C" void kernel_launch(void* const* d_in, const int* in_sizes, int n_in,
                              void* d_out, int out_size, void* d_ws, size_t ws_size,
                              hipStream_t stream) {
  const float* logits = (const float*)d_in[0];
  const float* labels = (const float*)d_in[1];
  const int*   pad    = (const int*)d_in[2];
  const int*   ad     = (const int*)d_in[3];

  char* ws = (char*)d_ws;
  unsigned char* qb = (unsigned char*)(ws);             // 2 MiB (fp8)
  unsigned char* kb = (unsigned char*)(ws + 2097152);   // 2 MiB (fp8)
  float*  cb   = (float*)(ws + 4194304);                // 32 KiB
  float*  gAll = (float*)(ws + 4227072);                // 32 KiB
  float*  gPos = (float*)(ws + 4259840);                // 32 KiB
  float*  out  = (float*)d_out;

  prep_kernel<<<4096, 256, 0, stream>>>(logits, labels, pad, qb, kb, cb, gAll, gPos);
  gemm_lse_kernel<<<dim3(64, 32), 512, 0, stream>>>(qb, kb, cb, ad, gAll, gPos);
  reduce_kernel<<<1, 1024, 0, stream>>>(gAll, gPos, pad, out);
}

// Round 2
// 118.384 us; speedup vs baseline: 1.0194x; 1.0194x over previous
//
#include <hip/hip_runtime.h>
#include <hip/hip_bf16.h>
#include <hip/hip_fp8.h>
#include <math.h>

typedef float f32x4 __attribute__((ext_vector_type(4)));
typedef int   i32x4 __attribute__((ext_vector_type(4)));
typedef int   v8i   __attribute__((ext_vector_type(8)));

constexpr int Nn = 8192;   // B*S
constexpr int Dd = 256;    // feature dim (== bytes per fp8 row)
constexpr float LOG2E     = 1.4426950408889634f;
constexpr float SIM_SCALE = 20.0f * LOG2E;   // (1/tau)*log2(e), tau=0.05
constexpr float SIM_BIAS  = -20.0f * LOG2E;  // fixed max = 1/tau (|q.k|<=1)
constexpr int   SCALE1    = 0x7F7F7F7F;      // E8M0 127 = 2^0 in every byte

// async global->LDS DMA, 16B/lane; LDS dst = wave-uniform base + lane*16.
typedef __attribute__((address_space(1))) const unsigned int gu32;
typedef __attribute__((address_space(3))) unsigned int lu32;
__device__ __forceinline__ void gload16(const unsigned char* g, unsigned char* l) {
  __builtin_amdgcn_global_load_lds((gu32*)(uintptr_t)g, (lu32*)(uintptr_t)l, 16, 0, 0);
}

// ---------------------------------------------------------------------------
// Kernel 1: L2-normalize rows -> fp8 e4m3; init cbias (SIM_BIAS pre-folded) /
// g_all / g_pos.  (R14 version -- correctness-verified.)
// ---------------------------------------------------------------------------
__global__ __launch_bounds__(256) void prep_kernel(const float* __restrict__ logits,
                                                   const float* __restrict__ labels,
                                                   const int* __restrict__ pad,
                                                   unsigned char* __restrict__ qb,
                                                   unsigned char* __restrict__ kb,
                                                   float* __restrict__ cbias,
                                                   float* __restrict__ g_all,
                                                   float* __restrict__ g_pos) {
  const int j = blockIdx.x * 256 + threadIdx.x;
  if (j < Nn) {
    cbias[j] = pad[j] ? SIM_BIAS : -1e30f;   // SIM_BIAS folded in (col term)
    g_all[j] = 0.0f;
    g_pos[j] = 0.0f;
  }

  const int gw   = (blockIdx.x * 256 + threadIdx.x) >> 6;
  const int lane = threadIdx.x & 63;
  const float* src;
  unsigned char* dst;
  int row;
  if (gw < Nn) { src = logits; dst = qb; row = gw; }
  else         { src = labels; dst = kb; row = gw - Nn; }

  const float4 v = *reinterpret_cast<const float4*>(src + (size_t)row * Dd + lane * 4);
  float ss = v.x * v.x + v.y * v.y + v.z * v.z + v.w * v.w;
#pragma unroll
  for (int m = 32; m >= 1; m >>= 1) ss += __shfl_xor(ss, m);
  const float scale = 1.0f / fmaxf(sqrtf(ss), 1e-12f);

  const __hip_fp8_e4m3 e0(v.x * scale);
  const __hip_fp8_e4m3 e1(v.y * scale);
  const __hip_fp8_e4m3 e2(v.z * scale);
  const __hip_fp8_e4m3 e3(v.w * scale);
  const unsigned int packed = (unsigned int)e0.__x |
                              ((unsigned int)e1.__x << 8) |
                              ((unsigned int)e2.__x << 16) |
                              ((unsigned int)e3.__x << 24);
  reinterpret_cast<unsigned int*>(dst + (size_t)row * Dd)[lane] = packed;
}

// ---------------------------------------------------------------------------
// Kernel 2: fused sim = Q K^T / tau + dual exp-sum epilogue (all & pos), fp8
// MX-scaled MFMA 16x16x128 (unit scales).
//
// R15: keep the R13 execution shape EXACTLY (256 thr, 2x2 waves, 64x64/wave,
// same DMA swizzle slot = g ^ (r&7), same fragment math), but each block
// covers 256 rows x 128 cols via TWO row-passes with the B panel resident:
//   - B (both K-halves, 32KB) staged once in prologue, reused by both passes
//   - A half (16KB) restaged per (pass, kk)
//   - L2-staged bytes: 268MB -> 197MB (-27%)  [largest pipe]
//   - occupancy preserved: 48KB LDS -> 3 blocks/CU; regs ~R13 -> 2-3 blk/CU
//     (R14's failure was 512-thr blocks at ~148 regs -> 1 block/CU)
// Epilogue per pass (rows complete per pass): R14-verified shfl_xor(8) fold
// -> 16 partials/row -> redA/redP (16KB) overlay the A region only; B lives.
// ---------------------------------------------------------------------------
__global__ __launch_bounds__(256) void gemm_lse_kernel(const unsigned char* __restrict__ qb,
                                                       const unsigned char* __restrict__ kb,
                                                       const float* __restrict__ cbias,
                                                       const int* __restrict__ ad,
                                                       float* __restrict__ g_all,
                                                       float* __restrict__ g_pos) {
  __shared__ unsigned char smem[49152];
  unsigned char* As = smem;              // 16KB: current A K-half (128 x 128B)
  // Bs halves at smem + 16384 + kk*16384 (2 x 16KB, resident whole kernel)
  float* redA = reinterpret_cast<float*>(smem);         // 8KB: 128 x 16
  float* redP = reinterpret_cast<float*>(smem) + 2048;  // 8KB: 128 x 16

  const int tid  = threadIdx.x;
  const int lane = tid & 63;
  const int w    = tid >> 6;        // 0..3
  const int wrow = (w >> 1) * 64;
  const int wcol = (w & 1) * 64;
  const int lq   = lane & 15;
  const int qd   = lane >> 4;
  const int rowBase = blockIdx.x * 256;   // 2 row-passes of 128
  const int colBase = blockIdx.y * 128;

  // staging constants (R13-verified): wave w, iter i fills 8 LDS rows;
  // lane l -> row +(l>>3), logical 16B group (l&7)^(l>>3) (linear LDS dst).
  const int srl = lane >> 3;
  const int cg  = (lane & 7) ^ srl;
  const unsigned char* gA0 = qb + (size_t)(rowBase + w * 32 + srl) * Dd + cg * 16;
  const unsigned char* gB0 = kb + (size_t)(colBase + w * 32 + srl) * Dd + cg * 16;

  // ---- prologue: stage B panel, both K-halves (resident) ----
#pragma unroll
  for (int kkb = 0; kkb < 2; ++kkb)
#pragma unroll
    for (int i = 0; i < 4; ++i)
      gload16(gB0 + (size_t)i * 8 * Dd + kkb * 128,
              &smem[16384 + kkb * 16384 + (w * 32 + i * 8) * 128]);

  // column metadata (fixed for the whole block)
  float colB[4];
  int colAd[4];
#pragma unroll
  for (int nt = 0; nt < 4; ++nt) {
    const int col = colBase + wcol + nt * 16 + lq;
    colB[nt]  = cbias[col];          // SIM_BIAS already folded in prep
    colAd[nt] = ad[col];
  }

  for (int pass = 0; pass < 2; ++pass) {
    const int rowOff = pass * 128;

    f32x4 c[4][4];
#pragma unroll
    for (int mt = 0; mt < 4; ++mt)
#pragma unroll
      for (int nt = 0; nt < 4; ++nt)
        c[mt][nt] = (f32x4){0.f, 0.f, 0.f, 0.f};

    for (int kk = 0; kk < 2; ++kk) {
      const int kOff = kk * 128;  // byte offset into the 256B row
      __syncthreads();  // prior readers of As region done (mfma / reduce)
#pragma unroll
      for (int i = 0; i < 4; ++i)
        gload16(gA0 + (size_t)(rowOff + i * 8) * Dd + kOff,
                &As[(w * 32 + i * 8) * 128]);
      __syncthreads();  // drains vmcnt (DMA) before fragment reads

      const int g0 = qd << 1;  // lane's first 16B group (K bytes qd*32..+15)
      v8i af[4];
#pragma unroll
      for (int mt = 0; mt < 4; ++mt) {
        const int r = wrow + mt * 16 + lq;
        const i32x4 lo = *reinterpret_cast<const i32x4*>(&As[r * 128 + ((g0 ^ (r & 7)) << 4)]);
        const i32x4 hi = *reinterpret_cast<const i32x4*>(&As[r * 128 + (((g0 + 1) ^ (r & 7)) << 4)]);
        af[mt] = (v8i){lo.x, lo.y, lo.z, lo.w, hi.x, hi.y, hi.z, hi.w};
      }
      const unsigned char* BsH = &smem[16384 + kk * 16384];
#pragma unroll
      for (int nt = 0; nt < 4; ++nt) {
        const int r = wcol + nt * 16 + lq;
        const i32x4 lo = *reinterpret_cast<const i32x4*>(&BsH[r * 128 + ((g0 ^ (r & 7)) << 4)]);
        const i32x4 hi = *reinterpret_cast<const i32x4*>(&BsH[r * 128 + (((g0 + 1) ^ (r & 7)) << 4)]);
        const v8i bfq = (v8i){lo.x, lo.y, lo.z, lo.w, hi.x, hi.y, hi.z, hi.w};
#pragma unroll
        for (int mt = 0; mt < 4; ++mt)
          c[mt][nt] = __builtin_amdgcn_mfma_scale_f32_16x16x128_f8f6f4(
              af[mt], bfq, c[mt][nt], 0, 0, 0, SCALE1, 0, SCALE1);
      }
    }

    // ---- epilogue for this pass's 128 rows ----
    __syncthreads();  // all waves done reading As before overlay as partials

#pragma unroll
    for (int mt = 0; mt < 4; ++mt) {
#pragma unroll
      for (int r = 0; r < 4; ++r) {
        const int row   = wrow + mt * 16 + qd * 4 + r;
        const int rowAd = ad[rowBase + rowOff + row];
        float a = 0.f, p = 0.f;
#pragma unroll
        for (int nt = 0; nt < 4; ++nt) {
          const float e = __builtin_amdgcn_exp2f(fmaf(c[mt][nt][r], SIM_SCALE, colB[nt]));
          a += e;
          p += (colAd[nt] == rowAd) ? e : 0.f;
        }
        // fold lanes lq and lq^8 (same row, disjoint nt-column sets)
        a += __shfl_xor(a, 8);
        p += __shfl_xor(p, 8);
        if (lq < 8) {
          const int idx = (w & 1) * 8 + lq;   // 16 partials per row
          const int g   = idx >> 2;
          const int gi  = idx & 3;
          const int off = row * 16 + ((g ^ (row & 3)) << 2) + gi;
          redA[off] = a;
          redP[off] = p;
        }
      }
    }
    __syncthreads();

    if (tid < 128) {
      const int row = tid;
      float a = 0.f, p = 0.f;
#pragma unroll
      for (int gg = 0; gg < 4; ++gg) {
        const int off = row * 16 + ((gg ^ (row & 3)) << 2);
        const f32x4 va = *reinterpret_cast<const f32x4*>(&redA[off]);
        const f32x4 vp = *reinterpret_cast<const f32x4*>(&redP[off]);
        a += (va[0] + va[1]) + (va[2] + va[3]);
        p += (vp[0] + vp[1]) + (vp[2] + vp[3]);
      }
      atomicAdd(&g_all[rowBase + rowOff + row], a);
      atomicAdd(&g_pos[rowBase + rowOff + row], p);
    }
    // next pass's first __syncthreads orders these reduce-reads before the
    // As region is restaged.
  }
}

// ---------------------------------------------------------------------------
// Kernel 3: loss = mean over valid rows of log(g_all) - log(g_pos).
// ---------------------------------------------------------------------------
__global__ __launch_bounds__(1024) void reduce_kernel(const float* __restrict__ g_all,
                                                      const float* __restrict__ g_pos,
                                                      const int* __restrict__ pad,
                                                      float* __restrict__ out) {
  __shared__ float sS[16], sC[16];
  const int t = threadIdx.x;
  float s = 0.f, c = 0.f;
  const float4* ga4 = (const float4*)g_all;
  const float4* gp4 = (const float4*)g_pos;
  const int4*   pd4 = (const int4*)pad;
  for (int i = t; i < Nn / 4; i += 1024) {
    const float4 ga = ga4[i];
    const float4 gp = gp4[i];
    const int4   pd = pd4[i];
    if (pd.x) { s += __logf(ga.x) - __logf(gp.x); c += 1.f; }
    if (pd.y) { s += __logf(ga.y) - __logf(gp.y); c += 1.f; }
    if (pd.z) { s += __logf(ga.z) - __logf(gp.z); c += 1.f; }
    if (pd.w) { s += __logf(ga.w) - __logf(gp.w); c += 1.f; }
  }
#pragma unroll
  for (int m = 32; m >= 1; m >>= 1) {
    s += __shfl_xor(s, m);
    c += __shfl_xor(c, m);
  }
  if ((t & 63) == 0) { sS[t >> 6] = s; sC[t >> 6] = c; }
  __syncthreads();
  if (t == 0) {
    float S = 0.f, C = 0.f;
#pragma unroll
    for (int i = 0; i < 16; ++i) { S += sS[i]; C += sC[i]; }
    out[0] = S / fmaxf(C, 1.0f);
  }
}

extern "C" void kernel_launch(void* const* d_in, const int* in_sizes, int n_in,
                              void* d_out, int out_size, void* d_ws, size_t ws_size,
                              hipStream_t stream) {
  const float* logits = (const float*)d_in[0];
  const float* labels = (const float*)d_in[1];
  const int*   pad    = (const int*)d_in[2];
  const int*   ad     = (const int*)d_in[3];

  char* ws = (char*)d_ws;
  unsigned char* qb = (unsigned char*)(ws);             // 2 MiB (fp8)
  unsigned char* kb = (unsigned char*)(ws + 2097152);   // 2 MiB (fp8)
  float*  cb   = (float*)(ws + 4194304);                // 32 KiB
  float*  gAll = (float*)(ws + 4227072);                // 32 KiB
  float*  gPos = (float*)(ws + 4259840);                // 32 KiB
  float*  out  = (float*)d_out;

  prep_kernel<<<4096, 256, 0, stream>>>(logits, labels, pad, qb, kb, cb, gAll, gPos);
  gemm_lse_kernel<<<dim3(32, 64), 256, 0, stream>>>(qb, kb, cb, ad, gAll, gPos);
  reduce_kernel<<<1, 1024, 0, stream>>>(gAll, gPos, pad, out);
}

// Round 3
// 104.156 us; speedup vs baseline: 1.1587x; 1.1366x over previous
//
#include <hip/hip_runtime.h>
#include <hip/hip_bf16.h>
#include <hip/hip_fp8.h>
#include <math.h>

typedef float f32x4 __attribute__((ext_vector_type(4)));
typedef int   i32x4 __attribute__((ext_vector_type(4)));
typedef int   v8i   __attribute__((ext_vector_type(8)));

constexpr int Nn = 8192;   // B*S
constexpr int Dd = 256;    // feature dim (== bytes per fp8 row)
constexpr float LOG2E     = 1.4426950408889634f;
constexpr float SIM_SCALE = 20.0f * LOG2E;   // (1/tau)*log2(e), tau=0.05
constexpr float SIM_BIAS  = -20.0f * LOG2E;  // fixed max = 1/tau (|q.k|<=1)
constexpr int   SCALE1    = 0x7F7F7F7F;      // E8M0 127 = 2^0 in every byte

// async global->LDS DMA, 16B/lane; LDS dst = wave-uniform base + lane*16.
typedef __attribute__((address_space(1))) const unsigned int gu32;
typedef __attribute__((address_space(3))) unsigned int lu32;
__device__ __forceinline__ void gload16(const unsigned char* g, unsigned char* l) {
  __builtin_amdgcn_global_load_lds((gu32*)(uintptr_t)g, (lu32*)(uintptr_t)l, 16, 0, 0);
}

// ---------------------------------------------------------------------------
// Kernel 1: L2-normalize rows -> fp8 e4m3; init cbias (SIM_BIAS pre-folded) /
// g_all / g_pos.  (Correctness-verified, unchanged.)
// ---------------------------------------------------------------------------
__global__ __launch_bounds__(256) void prep_kernel(const float* __restrict__ logits,
                                                   const float* __restrict__ labels,
                                                   const int* __restrict__ pad,
                                                   unsigned char* __restrict__ qb,
                                                   unsigned char* __restrict__ kb,
                                                   float* __restrict__ cbias,
                                                   float* __restrict__ g_all,
                                                   float* __restrict__ g_pos) {
  const int j = blockIdx.x * 256 + threadIdx.x;
  if (j < Nn) {
    cbias[j] = pad[j] ? SIM_BIAS : -1e30f;   // SIM_BIAS folded in (col term)
    g_all[j] = 0.0f;
    g_pos[j] = 0.0f;
  }

  const int gw   = (blockIdx.x * 256 + threadIdx.x) >> 6;
  const int lane = threadIdx.x & 63;
  const float* src;
  unsigned char* dst;
  int row;
  if (gw < Nn) { src = logits; dst = qb; row = gw; }
  else         { src = labels; dst = kb; row = gw - Nn; }

  const float4 v = *reinterpret_cast<const float4*>(src + (size_t)row * Dd + lane * 4);
  float ss = v.x * v.x + v.y * v.y + v.z * v.z + v.w * v.w;
#pragma unroll
  for (int m = 32; m >= 1; m >>= 1) ss += __shfl_xor(ss, m);
  const float scale = 1.0f / fmaxf(sqrtf(ss), 1e-12f);

  const __hip_fp8_e4m3 e0(v.x * scale);
  const __hip_fp8_e4m3 e1(v.y * scale);
  const __hip_fp8_e4m3 e2(v.z * scale);
  const __hip_fp8_e4m3 e3(v.w * scale);
  const unsigned int packed = (unsigned int)e0.__x |
                              ((unsigned int)e1.__x << 8) |
                              ((unsigned int)e2.__x << 16) |
                              ((unsigned int)e3.__x << 24);
  reinterpret_cast<unsigned int*>(dst + (size_t)row * Dd)[lane] = packed;
}

// ---------------------------------------------------------------------------
// Kernel 2 (R16 restructure): row-persistent blocks, register-accumulated LSE.
//
// Grid 64x8: block = 128 rows x 1024 cols (8 col-tiles of 128).
//   - A panel (128 x 256B, both K-halves) staged ONCE (32KB, resident)
//   - B tiles double-buffered (2 x 16KB), T3-lite schedule: per iteration
//     {stage B[t+1] | ds_read frags | 16 MFMA | (odd t) exp2-accumulate} then
//     ONE __syncthreads -- the drain's L2 latency is covered by the same
//     iteration's compute.  16 barriers/block total (was ~12 per 1/4 of this
//     work + contended mid-kernel atomic drains).
//   - a/p row-sums accumulate in 32 regs across col-tiles; ONE shfl-tree +
//     atomicAdd per row at kernel END (16-way contention, drained at retire).
//   - L2-staged bytes 197MB -> 144MB.
// Fragment math, DMA swizzle (slot = g ^ (r&7)), exp2 epilogue formula are
// byte-identical to the R13/R15-verified path.
// LDS 64KB -> 2 blocks/CU; launch_bounds(256,2) matches (256-reg budget).
// ---------------------------------------------------------------------------
__global__ __launch_bounds__(256, 2) void gemm_lse_kernel(const unsigned char* __restrict__ qb,
                                                          const unsigned char* __restrict__ kb,
                                                          const float* __restrict__ cbias,
                                                          const int* __restrict__ ad,
                                                          float* __restrict__ g_all,
                                                          float* __restrict__ g_pos) {
  __shared__ unsigned char smem[65536];
  // A halves: smem + kk*16384          (resident whole kernel)
  // B bufs  : smem + 32768 + buf*16384 (ping-pong)

  const int tid  = threadIdx.x;
  const int lane = tid & 63;
  const int w    = tid >> 6;        // 0..3
  const int wrow = (w >> 1) * 64;   // 0 or 64
  const int wcolL = (w & 1) * 64;   // 0 or 64 within the 128-col tile
  const int lq   = lane & 15;
  const int qd   = lane >> 4;
  const int rowBase = blockIdx.x * 128;
  const int colBase = blockIdx.y * 1024;   // 8 col-tiles of 128

  // staging constants (verified): wave w, iter i fills 8 LDS rows;
  // lane l -> row +(l>>3), logical 16B group (l&7)^(l>>3) (linear LDS dst).
  const int srl = lane >> 3;
  const int cg  = (lane & 7) ^ srl;
  const unsigned char* gA0 = qb + (size_t)(rowBase + w * 32 + srl) * Dd + cg * 16;
  const unsigned char* gB0 = kb + (size_t)(colBase + w * 32 + srl) * Dd + cg * 16;

  // ---- prologue: stage A (both K-halves, resident) + B tile for t=0 ----
#pragma unroll
  for (int kk = 0; kk < 2; ++kk)
#pragma unroll
    for (int i = 0; i < 4; ++i)
      gload16(gA0 + (size_t)i * 8 * Dd + kk * 128,
              &smem[kk * 16384 + (w * 32 + i * 8) * 128]);
#pragma unroll
  for (int i = 0; i < 4; ++i)   // ct=0, kk=0 -> buf 0
    gload16(gB0 + (size_t)i * 8 * Dd, &smem[32768 + (w * 32 + i * 8) * 128]);

  // per-thread row metadata (16 rows: mt x r)
  int rowAd[4][4];
#pragma unroll
  for (int mt = 0; mt < 4; ++mt)
#pragma unroll
    for (int r = 0; r < 4; ++r)
      rowAd[mt][r] = ad[rowBase + wrow + mt * 16 + qd * 4 + r];

  float apA[4][4], apP[4][4];
  f32x4 c[4][4];
#pragma unroll
  for (int mt = 0; mt < 4; ++mt)
#pragma unroll
    for (int r = 0; r < 4; ++r) {
      apA[mt][r] = 0.f;
      apP[mt][r] = 0.f;
      c[mt][r] = (f32x4){0.f, 0.f, 0.f, 0.f};
    }

  float colB[4];
  int colAd[4];

  __syncthreads();  // drain prologue stages

  // t = ct*2 + kk ; iteration computes (ct, kk) from B buf[t&1],
  // stages (ct', kk') = t+1 into buf[(t+1)&1].
  for (int t = 0; t < 16; ++t) {
    const int kk = t & 1;

    if (t + 1 < 16) {  // issue next B-tile stage (drained by end-of-iter sync)
      const int tn = t + 1;
      const unsigned char* g = gB0 + (size_t)((tn >> 1) * 128) * Dd + (tn & 1) * 128;
      unsigned char* dB = &smem[32768 + (tn & 1) * 16384 + (w * 32) * 128];
#pragma unroll
      for (int i = 0; i < 4; ++i)
        gload16(g + (size_t)i * 8 * Dd, dB + i * 8 * 128);
    }

    if (kk == 0) {  // prefetch this col-tile's column metadata (used at t+1)
      const int ct = t >> 1;
#pragma unroll
      for (int nt = 0; nt < 4; ++nt) {
        const int col = colBase + ct * 128 + wcolL + nt * 16 + lq;
        colB[nt]  = cbias[col];   // SIM_BIAS already folded in prep
        colAd[nt] = ad[col];
      }
    }

    const int g0 = qd << 1;  // lane's first 16B group (K bytes qd*32..+15)
    const unsigned char* Ah = &smem[kk * 16384];
    const unsigned char* Bh = &smem[32768 + (t & 1) * 16384];

    v8i af[4];
#pragma unroll
    for (int mt = 0; mt < 4; ++mt) {
      const int r = wrow + mt * 16 + lq;
      const i32x4 lo = *reinterpret_cast<const i32x4*>(&Ah[r * 128 + ((g0 ^ (r & 7)) << 4)]);
      const i32x4 hi = *reinterpret_cast<const i32x4*>(&Ah[r * 128 + (((g0 + 1) ^ (r & 7)) << 4)]);
      af[mt] = (v8i){lo.x, lo.y, lo.z, lo.w, hi.x, hi.y, hi.z, hi.w};
    }
#pragma unroll
    for (int nt = 0; nt < 4; ++nt) {
      const int r = wcolL + nt * 16 + lq;
      const i32x4 lo = *reinterpret_cast<const i32x4*>(&Bh[r * 128 + ((g0 ^ (r & 7)) << 4)]);
      const i32x4 hi = *reinterpret_cast<const i32x4*>(&Bh[r * 128 + (((g0 + 1) ^ (r & 7)) << 4)]);
      const v8i bfq = (v8i){lo.x, lo.y, lo.z, lo.w, hi.x, hi.y, hi.z, hi.w};
#pragma unroll
      for (int mt = 0; mt < 4; ++mt)
        c[mt][nt] = __builtin_amdgcn_mfma_scale_f32_16x16x128_f8f6f4(
            af[mt], bfq, c[mt][nt], 0, 0, 0, SCALE1, 0, SCALE1);
    }

    if (kk == 1) {  // col-tile complete: exp2-accumulate into registers
#pragma unroll
      for (int mt = 0; mt < 4; ++mt) {
#pragma unroll
        for (int r = 0; r < 4; ++r) {
          float a = 0.f, p = 0.f;
#pragma unroll
          for (int nt = 0; nt < 4; ++nt) {
            const float e = __builtin_amdgcn_exp2f(fmaf(c[mt][nt][r], SIM_SCALE, colB[nt]));
            a += e;
            p += (colAd[nt] == rowAd[mt][r]) ? e : 0.f;
          }
          apA[mt][r] += a;
          apP[mt][r] += p;
        }
      }
#pragma unroll
      for (int mt = 0; mt < 4; ++mt)
#pragma unroll
        for (int nt = 0; nt < 4; ++nt)
          c[mt][nt] = (f32x4){0.f, 0.f, 0.f, 0.f};
    }

    __syncthreads();  // drains this iter's B stage; orders buf reuse
  }

  // ---- final reduction: shfl-tree over the 16 lq lanes, then one atomic ----
#pragma unroll
  for (int mt = 0; mt < 4; ++mt) {
#pragma unroll
    for (int r = 0; r < 4; ++r) {
      float a = apA[mt][r], p = apP[mt][r];
#pragma unroll
      for (int m = 1; m < 16; m <<= 1) {
        a += __shfl_xor(a, m);
        p += __shfl_xor(p, m);
      }
      if (lq == 0) {
        const int row = rowBase + wrow + mt * 16 + qd * 4 + r;
        atomicAdd(&g_all[row], a);
        atomicAdd(&g_pos[row], p);
      }
    }
  }
}

// ---------------------------------------------------------------------------
// Kernel 3: loss = mean over valid rows of log(g_all) - log(g_pos).
// ---------------------------------------------------------------------------
__global__ __launch_bounds__(1024) void reduce_kernel(const float* __restrict__ g_all,
                                                      const float* __restrict__ g_pos,
                                                      const int* __restrict__ pad,
                                                      float* __restrict__ out) {
  __shared__ float sS[16], sC[16];
  const int t = threadIdx.x;
  float s = 0.f, c = 0.f;
  const float4* ga4 = (const float4*)g_all;
  const float4* gp4 = (const float4*)g_pos;
  const int4*   pd4 = (const int4*)pad;
  for (int i = t; i < Nn / 4; i += 1024) {
    const float4 ga = ga4[i];
    const float4 gp = gp4[i];
    const int4   pd = pd4[i];
    if (pd.x) { s += __logf(ga.x) - __logf(gp.x); c += 1.f; }
    if (pd.y) { s += __logf(ga.y) - __logf(gp.y); c += 1.f; }
    if (pd.z) { s += __logf(ga.z) - __logf(gp.z); c += 1.f; }
    if (pd.w) { s += __logf(ga.w) - __logf(gp.w); c += 1.f; }
  }
#pragma unroll
  for (int m = 32; m >= 1; m >>= 1) {
    s += __shfl_xor(s, m);
    c += __shfl_xor(c, m);
  }
  if ((t & 63) == 0) { sS[t >> 6] = s; sC[t >> 6] = c; }
  __syncthreads();
  if (t == 0) {
    float S = 0.f, C = 0.f;
#pragma unroll
    for (int i = 0; i < 16; ++i) { S += sS[i]; C += sC[i]; }
    out[0] = S / fmaxf(C, 1.0f);
  }
}

extern "C" void kernel_launch(void* const* d_in, const int* in_sizes, int n_in,
                              void* d_out, int out_size, void* d_ws, size_t ws_size,
                              hipStream_t stream) {
  const float* logits = (const float*)d_in[0];
  const float* labels = (const float*)d_in[1];
  const int*   pad    = (const int*)d_in[2];
  const int*   ad     = (const int*)d_in[3];

  char* ws = (char*)d_ws;
  unsigned char* qb = (unsigned char*)(ws);             // 2 MiB (fp8)
  unsigned char* kb = (unsigned char*)(ws + 2097152);   // 2 MiB (fp8)
  float*  cb   = (float*)(ws + 4194304);                // 32 KiB
  float*  gAll = (float*)(ws + 4227072);                // 32 KiB
  float*  gPos = (float*)(ws + 4259840);                // 32 KiB
  float*  out  = (float*)d_out;

  prep_kernel<<<4096, 256, 0, stream>>>(logits, labels, pad, qb, kb, cb, gAll, gPos);
  gemm_lse_kernel<<<dim3(64, 8), 256, 0, stream>>>(qb, kb, cb, ad, gAll, gPos);
  reduce_kernel<<<1, 1024, 0, stream>>>(gAll, gPos, pad, out);
}

// Round 4
// 102.213 us; speedup vs baseline: 1.1807x; 1.0190x over previous
//
#include <hip/hip_runtime.h>
#include <hip/hip_bf16.h>
#include <hip/hip_fp8.h>
#include <math.h>

typedef float f32x4 __attribute__((ext_vector_type(4)));
typedef int   i32x4 __attribute__((ext_vector_type(4)));
typedef int   v8i   __attribute__((ext_vector_type(8)));

constexpr int Nn = 8192;   // B*S
constexpr int Dd = 256;    // feature dim (== bytes per fp8 row)
constexpr float LOG2E     = 1.4426950408889634f;
constexpr float SIM_SCALE = 20.0f * LOG2E;   // (1/tau)*log2(e), tau=0.05
constexpr float SIM_BIAS  = -20.0f * LOG2E;  // fixed max = 1/tau (|q.k|<=1)
constexpr int   SCALE1    = 0x7F7F7F7F;      // E8M0 127 = 2^0 in every byte

// async global->LDS DMA, 16B/lane; LDS dst = wave-uniform base + lane*16.
typedef __attribute__((address_space(1))) const unsigned int gu32;
typedef __attribute__((address_space(3))) unsigned int lu32;
__device__ __forceinline__ void gload16(const unsigned char* g, unsigned char* l) {
  __builtin_amdgcn_global_load_lds((gu32*)(uintptr_t)g, (lu32*)(uintptr_t)l, 16, 0, 0);
}

// ---------------------------------------------------------------------------
// Kernel 1: L2-normalize rows -> fp8 e4m3; init cbias (SIM_BIAS pre-folded) /
// g_all / g_pos.  (Correctness-verified, unchanged.)
// ---------------------------------------------------------------------------
__global__ __launch_bounds__(256) void prep_kernel(const float* __restrict__ logits,
                                                   const float* __restrict__ labels,
                                                   const int* __restrict__ pad,
                                                   unsigned char* __restrict__ qb,
                                                   unsigned char* __restrict__ kb,
                                                   float* __restrict__ cbias,
                                                   float* __restrict__ g_all,
                                                   float* __restrict__ g_pos) {
  const int j = blockIdx.x * 256 + threadIdx.x;
  if (j < Nn) {
    cbias[j] = pad[j] ? SIM_BIAS : -1e30f;   // SIM_BIAS folded in (col term)
    g_all[j] = 0.0f;
    g_pos[j] = 0.0f;
  }

  const int gw   = (blockIdx.x * 256 + threadIdx.x) >> 6;
  const int lane = threadIdx.x & 63;
  const float* src;
  unsigned char* dst;
  int row;
  if (gw < Nn) { src = logits; dst = qb; row = gw; }
  else         { src = labels; dst = kb; row = gw - Nn; }

  const float4 v = *reinterpret_cast<const float4*>(src + (size_t)row * Dd + lane * 4);
  float ss = v.x * v.x + v.y * v.y + v.z * v.z + v.w * v.w;
#pragma unroll
  for (int m = 32; m >= 1; m >>= 1) ss += __shfl_xor(ss, m);
  const float scale = 1.0f / fmaxf(sqrtf(ss), 1e-12f);

  const __hip_fp8_e4m3 e0(v.x * scale);
  const __hip_fp8_e4m3 e1(v.y * scale);
  const __hip_fp8_e4m3 e2(v.z * scale);
  const __hip_fp8_e4m3 e3(v.w * scale);
  const unsigned int packed = (unsigned int)e0.__x |
                              ((unsigned int)e1.__x << 8) |
                              ((unsigned int)e2.__x << 16) |
                              ((unsigned int)e3.__x << 24);
  reinterpret_cast<unsigned int*>(dst + (size_t)row * Dd)[lane] = packed;
}

// ---------------------------------------------------------------------------
// Kernel 2 (R17): R16 schedule (row-persistent 128x1024 blocks, B ping-pong,
// register LSE accumulate, atomics at retire) with the LDS/VALU overhead cut:
//   (a) A fragments hoisted to registers ONCE (afReg[2][4], 64 VGPR):
//       A-side ds_reads 8/iter -> 0; LDS read pipe drops below MFMA pipe.
//   (b) B fragments ds_read directly into the v8i halves (no mov-packing).
//   (c) t-loop unrolled by kk: first MFMA of each col-tile takes C=0 literal
//       (no 64-reg accumulator zeroing); all indices compile-time.
// Fragment math, DMA swizzle (slot = g ^ (r&7)), exp2 formula: byte-identical
// to the R13..R16-verified path.  Est. regs ~210 < 256 @ 2 blocks/CU.
// NOTE: r&7 == lq&7 for all fragment rows (wrow/wcolL/mt*16 are multiples of
// 8), so each lane's two slot offsets s0/s1 are loop-invariant.
// ---------------------------------------------------------------------------
__global__ __launch_bounds__(256, 2) void gemm_lse_kernel(const unsigned char* __restrict__ qb,
                                                          const unsigned char* __restrict__ kb,
                                                          const float* __restrict__ cbias,
                                                          const int* __restrict__ ad,
                                                          float* __restrict__ g_all,
                                                          float* __restrict__ g_pos) {
  __shared__ unsigned char smem[65536];
  // A transit: smem[0..32768)  (dead after the one-time fragment hoist)
  // B bufs  : smem + 32768 + p*16384 (ping-pong, p = kk parity)

  const int tid  = threadIdx.x;
  const int lane = tid & 63;
  const int w    = tid >> 6;        // 0..3
  const int wrow = (w >> 1) * 64;   // 0 or 64
  const int wcolL = (w & 1) * 64;   // 0 or 64 within the 128-col tile
  const int lq   = lane & 15;
  const int qd   = lane >> 4;
  const int rowBase = blockIdx.x * 128;
  const int colBase = blockIdx.y * 1024;   // 8 col-tiles of 128

  // staging constants (verified): wave w, iter i fills 8 LDS rows;
  // lane l -> row +(l>>3), logical 16B group (l&7)^(l>>3) (linear LDS dst).
  const int srl = lane >> 3;
  const int cg  = (lane & 7) ^ srl;
  const unsigned char* gA0 = qb + (size_t)(rowBase + w * 32 + srl) * Dd + cg * 16;
  const unsigned char* gB0 = kb + (size_t)(colBase + w * 32 + srl) * Dd + cg * 16;

  // ---- prologue: stage A (both K-halves) + B(0, kk=0) ----
#pragma unroll
  for (int kk = 0; kk < 2; ++kk)
#pragma unroll
    for (int i = 0; i < 4; ++i)
      gload16(gA0 + (size_t)i * 8 * Dd + kk * 128,
              &smem[kk * 16384 + (w * 32 + i * 8) * 128]);
#pragma unroll
  for (int i = 0; i < 4; ++i)
    gload16(gB0 + (size_t)i * 8 * Dd, &smem[32768 + (w * 32 + i * 8) * 128]);

  // per-thread row metadata (16 rows: mt x r)
  int rowAd[4][4];
#pragma unroll
  for (int mt = 0; mt < 4; ++mt)
#pragma unroll
    for (int r = 0; r < 4; ++r)
      rowAd[mt][r] = ad[rowBase + wrow + mt * 16 + qd * 4 + r];

  float apA[4][4], apP[4][4];
#pragma unroll
  for (int mt = 0; mt < 4; ++mt)
#pragma unroll
    for (int r = 0; r < 4; ++r) {
      apA[mt][r] = 0.f;
      apP[mt][r] = 0.f;
    }

  __syncthreads();  // drains prologue DMA (A both halves + B(0,0))

  // ---- one-time A fragment hoist (A LDS region dead afterwards) ----
  const int g0 = qd << 1;
  const int sl = lq & 7;                 // == r&7 for every fragment row
  const int s0 = (g0 ^ sl) << 4;
  const int s1 = ((g0 + 1) ^ sl) << 4;

  v8i afReg[2][4];
#pragma unroll
  for (int kk = 0; kk < 2; ++kk) {
    const unsigned char* Ah = &smem[kk * 16384];
#pragma unroll
    for (int mt = 0; mt < 4; ++mt) {
      const int rb = (wrow + mt * 16 + lq) * 128;
      i32x4* ph = reinterpret_cast<i32x4*>(&afReg[kk][mt]);
      ph[0] = *reinterpret_cast<const i32x4*>(&Ah[rb + s0]);
      ph[1] = *reinterpret_cast<const i32x4*>(&Ah[rb + s1]);
    }
  }

  const f32x4 CZ = (f32x4){0.f, 0.f, 0.f, 0.f};
  f32x4 c[4][4];
  float colB[4];
  int colAd[4];

  for (int ct = 0; ct < 8; ++ct) {
    // ================= kk = 0 (B from buf0; C-in = 0) =================
    {
      // stage B(ct, kk=1) -> buf1 (consumed after the barrier below)
      const unsigned char* g = gB0 + (size_t)(ct * 128) * Dd + 128;
      unsigned char* dB = &smem[32768 + 16384 + (w * 32) * 128];
#pragma unroll
      for (int i = 0; i < 4; ++i)
        gload16(g + (size_t)i * 8 * Dd, dB + i * 8 * 128);

      // this col-tile's column metadata (used in the kk=1 epilogue)
#pragma unroll
      for (int nt = 0; nt < 4; ++nt) {
        const int col = colBase + ct * 128 + wcolL + nt * 16 + lq;
        colB[nt]  = cbias[col];   // SIM_BIAS already folded in prep
        colAd[nt] = ad[col];
      }

      const unsigned char* Bh = &smem[32768];
#pragma unroll
      for (int nt = 0; nt < 4; ++nt) {
        const int rb = (wcolL + nt * 16 + lq) * 128;
        v8i bf;
        i32x4* pb = reinterpret_cast<i32x4*>(&bf);
        pb[0] = *reinterpret_cast<const i32x4*>(&Bh[rb + s0]);
        pb[1] = *reinterpret_cast<const i32x4*>(&Bh[rb + s1]);
#pragma unroll
        for (int mt = 0; mt < 4; ++mt)
          c[mt][nt] = __builtin_amdgcn_mfma_scale_f32_16x16x128_f8f6f4(
              afReg[0][mt], bf, CZ, 0, 0, 0, SCALE1, 0, SCALE1);
      }
      __syncthreads();  // drains B(ct,1) DMA; orders buf0 reuse
    }

    // ================= kk = 1 (B from buf1; accumulate) =================
    {
      if (ct < 7) {  // stage B(ct+1, kk=0) -> buf0
        const unsigned char* g = gB0 + (size_t)((ct + 1) * 128) * Dd;
        unsigned char* dB = &smem[32768 + (w * 32) * 128];
#pragma unroll
        for (int i = 0; i < 4; ++i)
          gload16(g + (size_t)i * 8 * Dd, dB + i * 8 * 128);
      }

      const unsigned char* Bh = &smem[32768 + 16384];
#pragma unroll
      for (int nt = 0; nt < 4; ++nt) {
        const int rb = (wcolL + nt * 16 + lq) * 128;
        v8i bf;
        i32x4* pb = reinterpret_cast<i32x4*>(&bf);
        pb[0] = *reinterpret_cast<const i32x4*>(&Bh[rb + s0]);
        pb[1] = *reinterpret_cast<const i32x4*>(&Bh[rb + s1]);
#pragma unroll
        for (int mt = 0; mt < 4; ++mt)
          c[mt][nt] = __builtin_amdgcn_mfma_scale_f32_16x16x128_f8f6f4(
              afReg[1][mt], bf, c[mt][nt], 0, 0, 0, SCALE1, 0, SCALE1);
      }

      // ---- epilogue for col-tile ct: exp2-accumulate into registers ----
#pragma unroll
      for (int mt = 0; mt < 4; ++mt) {
#pragma unroll
        for (int r = 0; r < 4; ++r) {
          float a = 0.f, p = 0.f;
#pragma unroll
          for (int nt = 0; nt < 4; ++nt) {
            const float e = __builtin_amdgcn_exp2f(fmaf(c[mt][nt][r], SIM_SCALE, colB[nt]));
            a += e;
            p += (colAd[nt] == rowAd[mt][r]) ? e : 0.f;
          }
          apA[mt][r] += a;
          apP[mt][r] += p;
        }
      }
      __syncthreads();  // drains B(ct+1,0) DMA; orders buf1 reuse
    }
  }

  // ---- final reduction: shfl-tree over the 16 lq lanes, then one atomic ----
#pragma unroll
  for (int mt = 0; mt < 4; ++mt) {
#pragma unroll
    for (int r = 0; r < 4; ++r) {
      float a = apA[mt][r], p = apP[mt][r];
#pragma unroll
      for (int m = 1; m < 16; m <<= 1) {
        a += __shfl_xor(a, m);
        p += __shfl_xor(p, m);
      }
      if (lq == 0) {
        const int row = rowBase + wrow + mt * 16 + qd * 4 + r;
        atomicAdd(&g_all[row], a);
        atomicAdd(&g_pos[row], p);
      }
    }
  }
}

// ---------------------------------------------------------------------------
// Kernel 3: loss = mean over valid rows of log(g_all) - log(g_pos).
// ---------------------------------------------------------------------------
__global__ __launch_bounds__(1024) void reduce_kernel(const float* __restrict__ g_all,
                                                      const float* __restrict__ g_pos,
                                                      const int* __restrict__ pad,
                                                      float* __restrict__ out) {
  __shared__ float sS[16], sC[16];
  const int t = threadIdx.x;
  float s = 0.f, c = 0.f;
  const float4* ga4 = (const float4*)g_all;
  const float4* gp4 = (const float4*)g_pos;
  const int4*   pd4 = (const int4*)pad;
  for (int i = t; i < Nn / 4; i += 1024) {
    const float4 ga = ga4[i];
    const float4 gp = gp4[i];
    const int4   pd = pd4[i];
    if (pd.x) { s += __logf(ga.x) - __logf(gp.x); c += 1.f; }
    if (pd.y) { s += __logf(ga.y) - __logf(gp.y); c += 1.f; }
    if (pd.z) { s += __logf(ga.z) - __logf(gp.z); c += 1.f; }
    if (pd.w) { s += __logf(ga.w) - __logf(gp.w); c += 1.f; }
  }
#pragma unroll
  for (int m = 32; m >= 1; m >>= 1) {
    s += __shfl_xor(s, m);
    c += __shfl_xor(c, m);
  }
  if ((t & 63) == 0) { sS[t >> 6] = s; sC[t >> 6] = c; }
  __syncthreads();
  if (t == 0) {
    float S = 0.f, C = 0.f;
#pragma unroll
    for (int i = 0; i < 16; ++i) { S += sS[i]; C += sC[i]; }
    out[0] = S / fmaxf(C, 1.0f);
  }
}

extern "C" void kernel_launch(void* const* d_in, const int* in_sizes, int n_in,
                              void* d_out, int out_size, void* d_ws, size_t ws_size,
                              hipStream_t stream) {
  const float* logits = (const float*)d_in[0];
  const float* labels = (const float*)d_in[1];
  const int*   pad    = (const int*)d_in[2];
  const int*   ad     = (const int*)d_in[3];

  char* ws = (char*)d_ws;
  unsigned char* qb = (unsigned char*)(ws);             // 2 MiB (fp8)
  unsigned char* kb = (unsigned char*)(ws + 2097152);   // 2 MiB (fp8)
  float*  cb   = (float*)(ws + 4194304);                // 32 KiB
  float*  gAll = (float*)(ws + 4227072);                // 32 KiB
  float*  gPos = (float*)(ws + 4259840);                // 32 KiB
  float*  out  = (float*)d_out;

  prep_kernel<<<4096, 256, 0, stream>>>(logits, labels, pad, qb, kb, cb, gAll, gPos);
  gemm_lse_kernel<<<dim3(64, 8), 256, 0, stream>>>(qb, kb, cb, ad, gAll, gPos);
  reduce_kernel<<<1, 1024, 0, stream>>>(gAll, gPos, pad, out);
}